// Round 5
// baseline (83.089 us; speedup 1.0000x reference)
//
#include <hip/hip_runtime.h>

// TriAffine: S[b,x,y,z] = sum_{i,k,j} xb[b,x,i] z[b,z,k] W[i,k,j] yb[b,y,j]
// B=2, L=256, N_IN=128. Output [2,256,256,256] f32 (134 MB).
//
// Padded flat axis n' = k*136 + j (j in 0..128 real, 129..135 zero-pad):
//  wtrans : Wt[n'][i] bf16 (pad rows zeroed) + x,y,z->bf16
//  stage1 : A2[bx][n'] = sum_{i<128} x[bx,i]*Wt[n'][i] + Wt[n'][128]  (flat GEMM)
//  stage2 : 1024 blocks (bx x y-half), 256 thr, 4 blocks/CU:
//           A2 row-layout == LDS layout -> pure float4 staging copy;
//           phaseA: P'[k,y] (32 y/wave); P'-> LDS [yloc][132] (aliases A2);
//           phaseB: wave owns 64 z x 128 y; z frags in regs; S = sum_k z*P'.

typedef __bf16 bf16x8 __attribute__((ext_vector_type(8)));
typedef short short4_t __attribute__((ext_vector_type(4)));
typedef float f32x4 __attribute__((ext_vector_type(4)));
typedef unsigned short ushort4_t __attribute__((ext_vector_type(4)));

#define LL 256
#define NI 128
#define NFLATP 17408           // 128 * 136 (padded (k,j) axis)
#define KJ_STRIDE 136          // j-stride within A2 row / LDS (272B, 16B-mult, bank-optimal b128)
#define WT_STRIDE 136          // Wt row stride (i-dim 129 -> 136)
#define P_STRIDE 132           // P' LDS k-stride (264B, 8B-mult, bank-optimal b64)

__device__ __forceinline__ unsigned short f2bf(float f) {
    unsigned u = __builtin_bit_cast(unsigned, f);
    u += 0x7FFFu + ((u >> 16) & 1u);   // RNE
    return (unsigned short)(u >> 16);
}
__device__ __forceinline__ float bf2f(unsigned short h) {
    return __builtin_bit_cast(float, (unsigned)h << 16);
}

// ---------------- wtrans + prep ----------------
// blocks 0..135: Wt[n'][i] for an n'-tile of 128 (j>128 -> 0).
// blocks 136..327: x,y,z f32 -> bf16.
__global__ __launch_bounds__(256) void wtrans_prep_kernel(const float* __restrict__ W,
                                                          const float* __restrict__ x,
                                                          const float* __restrict__ y,
                                                          const float* __restrict__ z,
                                                          unsigned short* __restrict__ Wt,
                                                          unsigned short* __restrict__ xyz) {
    const int blk = blockIdx.x, tid = threadIdx.x;
    if (blk < 136) {
        const int n0 = blk * 128 + ((tid & 31) << 2);   // multiple of 4; 4-group never crosses a row (136%4==0)
        const int isub = tid >> 5;
        const int k = n0 / KJ_STRIDE;
        const int j0 = n0 - k * KJ_STRIDE;              // 0,4,...,132
        const float* wrow = W + (size_t)k * 129;        // + i*16512 below
#pragma unroll    // issue all HBM loads up-front
        for (int it = 0; it < 17; ++it) {
            int i = it * 8 + isub;
            if (i <= 128) {
                const float* src = wrow + (size_t)i * 16512;
#pragma unroll
                for (int c = 0; c < 4; ++c) {
                    int j = j0 + c;
                    float v = (j <= 128) ? src[j] : 0.f;
                    Wt[(size_t)(n0 + c) * WT_STRIDE + i] = f2bf(v);
                }
            }
        }
    } else {
        int t = (blk - 136) * 256 + tid;       // 192 prep blocks
        int base = t * 4;
        int which = base >> 16;
        int local = base & 65535;
        const float* s = (which == 0) ? x : (which == 1) ? y : z;
        float4 v = *(const float4*)(s + local);
        ushort4_t o;
        o[0] = f2bf(v.x); o[1] = f2bf(v.y); o[2] = f2bf(v.z); o[3] = f2bf(v.w);
        *(ushort4_t*)(xyz + base) = o;
    }
}

// ---------------- stage1: flat GEMM A2[bx][n'] ----------------
// grid (4 bxg, 136 nb), 256 thr (4 waves). Wave: 32 n'-rows x 128 bx-cols.
__global__ __launch_bounds__(256) void stage1_kernel(const unsigned short* __restrict__ Wt,
                                                     const unsigned short* __restrict__ xbf,
                                                     unsigned short* __restrict__ A2g) {
    const int bxg = blockIdx.x;            // 0..3
    const int nb  = blockIdx.y;            // 0..135
    const int tid = threadIdx.x;
    const int wv = tid >> 6, lane = tid & 63;
    const int l15 = lane & 15, h = lane >> 4;
    const int nbase = nb * 128 + wv * 32;

    bf16x8 af[2][4];
#pragma unroll
    for (int nt = 0; nt < 2; ++nt)
#pragma unroll
        for (int is = 0; is < 4; ++is)
            af[nt][is] = *(const bf16x8*)(Wt + (size_t)(nbase + nt * 16 + l15) * WT_STRIDE + is * 32 + 8 * h);

    f32x4 acc[2][8];
#pragma unroll
    for (int nt = 0; nt < 2; ++nt) {
        f32x4 binit;
#pragma unroll
        for (int r = 0; r < 4; ++r)
            binit[r] = bf2f(Wt[(size_t)(nbase + nt * 16 + 4 * h + r) * WT_STRIDE + 128]);
#pragma unroll
        for (int ct = 0; ct < 8; ++ct) acc[nt][ct] = binit;
    }

#pragma unroll
    for (int is = 0; is < 4; ++is)
#pragma unroll
        for (int ct = 0; ct < 8; ++ct) {
            bf16x8 xf = *(const bf16x8*)(xbf + (bxg * 128 + ct * 16 + l15) * NI + is * 32 + 8 * h);
            acc[0][ct] = __builtin_amdgcn_mfma_f32_16x16x32_bf16(af[0][is], xf, acc[0][ct], 0, 0, 0);
            acc[1][ct] = __builtin_amdgcn_mfma_f32_16x16x32_bf16(af[1][is], xf, acc[1][ct], 0, 0, 0);
        }

#pragma unroll
    for (int nt = 0; nt < 2; ++nt)
#pragma unroll
        for (int ct = 0; ct < 8; ++ct) {
            ushort4_t o;
#pragma unroll
            for (int r = 0; r < 4; ++r) o[r] = f2bf(acc[nt][ct][r]);
            *(ushort4_t*)(A2g + (size_t)(bxg * 128 + ct * 16 + l15) * NFLATP + nbase + nt * 16 + 4 * h) = o;
        }
}

// ---------------- stage2: 1024 blocks (bx, y-half) -> S[y_half, z] 128x256 ----------------
__global__ __launch_bounds__(256, 4) void stage2_kernel(const unsigned short* __restrict__ ybf,
                                                        const unsigned short* __restrict__ zbf,
                                                        const unsigned short* __restrict__ A2g,
                                                        float* __restrict__ out) {
    const int bx  = blockIdx.x >> 1;       // b*256 + x
    const int yh  = blockIdx.x & 1;        // y-half
    const int b   = bx >> 8;
    const int tid = threadIdx.x;
    const int wv = tid >> 6, lane = tid & 63;
    const int l15 = lane & 15, h = lane >> 4;

    __shared__ __align__(16) unsigned short SH[NFLATP];   // 34816 B; P-half aliases after phaseA

    {   // pure vector staging: A2 row layout == LDS layout
        const float4* src = (const float4*)(A2g + (size_t)bx * NFLATP);
        float4* dst = (float4*)SH;
        for (int t = tid; t < NFLATP / 8; t += 256) dst[t] = src[t];
    }
    __syncthreads();

    const unsigned short* yb = ybf + b * LL * NI;
    const unsigned short* zb = zbf + b * LL * NI;
    const int y0 = wv * 32;                // local y base (wave owns 32 of 128)

    // ---- Phase A: P'[k,yloc] = sum_j A2[k,j]*y[y,j] + A2[k,128] ----
    f32x4 accP[8][2];                      // [k-tile][y-tile]; lane: y=l15(col), k=4h+r(row)
#pragma unroll
    for (int kt = 0; kt < 8; ++kt)
#pragma unroll
        for (int r = 0; r < 4; ++r) {
            float bias = bf2f(SH[(kt * 16 + 4 * h + r) * KJ_STRIDE + 128]);
            accP[kt][0][r] = bias; accP[kt][1][r] = bias;
        }
#pragma unroll
    for (int js = 0; js < 4; ++js) {
        bf16x8 yf[2];
#pragma unroll
        for (int yt = 0; yt < 2; ++yt)
            yf[yt] = *(const bf16x8*)(yb + (yh * 128 + y0 + yt * 16 + l15) * NI + js * 32 + 8 * h);
#pragma unroll
        for (int kt = 0; kt < 8; ++kt) {
            bf16x8 af = *(const bf16x8*)&SH[(kt * 16 + l15) * KJ_STRIDE + js * 32 + 8 * h];
            accP[kt][0] = __builtin_amdgcn_mfma_f32_16x16x32_bf16(af, yf[0], accP[kt][0], 0, 0, 0);
            accP[kt][1] = __builtin_amdgcn_mfma_f32_16x16x32_bf16(af, yf[1], accP[kt][1], 0, 0, 0);
        }
    }
    __syncthreads();   // all waves done reading A2 region

    // ---- P' -> LDS [yloc][P_STRIDE] bf16 ----
#pragma unroll
    for (int kt = 0; kt < 8; ++kt)
#pragma unroll
        for (int yt = 0; yt < 2; ++yt) {
            unsigned lo = (unsigned)f2bf(accP[kt][yt][0]) | ((unsigned)f2bf(accP[kt][yt][1]) << 16);
            unsigned hi = (unsigned)f2bf(accP[kt][yt][2]) | ((unsigned)f2bf(accP[kt][yt][3]) << 16);
            uint2 v; v.x = lo; v.y = hi;
            *(uint2*)&SH[(y0 + yt * 16 + l15) * P_STRIDE + kt * 16 + 4 * h] = v;
        }

    // z fragments: wave owns 64 z-rows, loaded once (overlaps ds_writes above)
    const int z0 = wv * 64;
    short4_t zf[4][8];
#pragma unroll
    for (int zt = 0; zt < 4; ++zt)
#pragma unroll
        for (int kt = 0; kt < 8; ++kt)
            zf[zt][kt] = *(const short4_t*)(zb + (z0 + zt * 16 + l15) * NI + kt * 16 + 4 * h);

    __syncthreads();   // P' visible

    // ---- Phase B: S[y,z] = sum_k z[z,k]*P'[k,y]; wave: 64 z x 128 y ----
    float* outb = out + (size_t)bx * (LL * LL) + (size_t)yh * 128 * LL;
#pragma unroll 1
    for (int yti = 0; yti < 8; ++yti) {
        const int yloc = yti * 16 + l15;         // this lane's local y (col)
        f32x4 acc2[4];
#pragma unroll
        for (int zt = 0; zt < 4; ++zt) { acc2[zt][0] = 0.f; acc2[zt][1] = 0.f; acc2[zt][2] = 0.f; acc2[zt][3] = 0.f; }
#pragma unroll
        for (int kt = 0; kt < 8; ++kt) {
            short4_t pB = *(const short4_t*)&SH[yloc * P_STRIDE + kt * 16 + 4 * h];
#pragma unroll
            for (int zt = 0; zt < 4; ++zt)
                acc2[zt] = __builtin_amdgcn_mfma_f32_16x16x16bf16_1k(zf[zt][kt], pB, acc2[zt], 0, 0, 0);
        }
#pragma unroll
        for (int zt = 0; zt < 4; ++zt)
            *(f32x4*)(outb + (size_t)yloc * LL + z0 + zt * 16 + 4 * h) = acc2[zt];
    }
}

extern "C" void kernel_launch(void* const* d_in, const int* in_sizes, int n_in,
                              void* d_out, int out_size, void* d_ws, size_t ws_size,
                              hipStream_t stream) {
    const float* x = (const float*)d_in[0];
    const float* y = (const float*)d_in[1];
    const float* z = (const float*)d_in[2];
    const float* W = (const float*)d_in[3];   // [129][128][129][1] = [129][16512]
    float* out = (float*)d_out;

    unsigned short* xbf = (unsigned short*)d_ws;             // 65536
    unsigned short* ybf = xbf + 65536;                       // 65536
    unsigned short* zbf = ybf + 65536;                       // 65536
    unsigned short* Wt  = zbf + 65536;                       // 17408*136 (~4.7 MB)
    unsigned short* A2g = Wt + (size_t)NFLATP * WT_STRIDE;   // 512*17408 (~17.8 MB)

    wtrans_prep_kernel<<<328, 256, 0, stream>>>(W, x, y, z, Wt, xbf);
    stage1_kernel<<<dim3(4, 136), 256, 0, stream>>>(Wt, xbf, A2g);
    stage2_kernel<<<1024, 256, 0, stream>>>(ybf, zbf, A2g, out);
}